// Round 5
// baseline (413.320 us; speedup 1.0000x reference)
//
#include <hip/hip_runtime.h>
#include <stdint.h>

#define TS 2048
#define DM 2048
#define NH 16
#define DH 128

typedef unsigned short u16t;
typedef __attribute__((ext_vector_type(8))) short short8;
typedef __attribute__((ext_vector_type(4))) float f32x4;
typedef __attribute__((ext_vector_type(4))) unsigned int u32x4;

__device__ __forceinline__ float bf2f(u16t b) {
  return __uint_as_float(((unsigned int)b) << 16);
}
__device__ __forceinline__ u16t f2bf(float f) {
  unsigned int u = __float_as_uint(f);
  u += 0x7FFFu + ((u >> 16) & 1u);   // round-to-nearest-even
  return (u16t)(u >> 16);
}

// async global->LDS, 16B per lane. LDS dest = wave-uniform base + lane*16.
__device__ __forceinline__ void async_copy16(const u16t* g, u16t* l) {
  __builtin_amdgcn_global_load_lds((const __attribute__((address_space(1))) void*)g,
                                   (__attribute__((address_space(3))) void*)l, 16, 0, 0);
}

// ---------------- fp32 weights -> bf16 (4 matrices, ws) ----------------
__global__ __launch_bounds__(256) void cast_weights(const float* __restrict__ W0,
                                                    const float* __restrict__ W1,
                                                    const float* __restrict__ W2,
                                                    const float* __restrict__ W3,
                                                    u16t* __restrict__ out) {
  const int idx = blockIdx.x * 256 + threadIdx.x;   // 4M threads, 4 elems each
  const int mat = idx >> 20;
  const size_t off = (size_t)(idx & 0xFFFFF) * 4;
  const float* W = (mat == 0) ? W0 : (mat == 1) ? W1 : (mat == 2) ? W2 : W3;
  const f32x4 v = *(const f32x4*)(W + off);
  union { u16t s[4]; uint64_t u; } o;
#pragma unroll
  for (int i = 0; i < 4; ++i) o.s[i] = f2bf(v[i]);
  *(uint64_t*)(out + (size_t)mat * (DM * DM) + off) = o.u;
}

// ---------------- RMSNorm: h = bf16( ln_w * x * rsqrt(mean(x^2)+eps) ) ----------------
__global__ __launch_bounds__(256) void rmsnorm_kernel(const float* __restrict__ x,
                                                      const float* __restrict__ w,
                                                      u16t* __restrict__ h) {
  const int row = blockIdx.x;
  const int tid = threadIdx.x;
  const float* xr = x + (size_t)row * DM + tid * 8;
  f32x4 v0 = *(const f32x4*)(xr);
  f32x4 v1 = *(const f32x4*)(xr + 4);
  float f[8];
#pragma unroll
  for (int i = 0; i < 4; ++i) { f[i] = v0[i]; f[i + 4] = v1[i]; }
  float ss = 0.f;
#pragma unroll
  for (int i = 0; i < 8; ++i) ss += f[i] * f[i];
#pragma unroll
  for (int off = 1; off < 64; off <<= 1) ss += __shfl_xor(ss, off, 64);
  __shared__ float wsum[4];
  if ((tid & 63) == 0) wsum[tid >> 6] = ss;
  __syncthreads();
  float tot = wsum[0] + wsum[1] + wsum[2] + wsum[3];
  float rs = rsqrtf(tot * (1.0f / DM) + 1e-5f);
  f32x4 w0 = *(const f32x4*)(w + tid * 8);
  f32x4 w1 = *(const f32x4*)(w + tid * 8 + 4);
  u32x4 o;
#pragma unroll
  for (int i = 0; i < 4; ++i) {
    unsigned int lo = f2bf(f[2 * i]     * ((2 * i     < 4) ? w0[2 * i]     : w1[2 * i - 4]) * rs);
    unsigned int hi = f2bf(f[2 * i + 1] * ((2 * i + 1 < 4) ? w0[2 * i + 1] : w1[2 * i - 3]) * rs);
    o[i] = lo | (hi << 16);
  }
  *(u32x4*)(h + (size_t)row * DM + tid * 8) = o;
}

// ---------------- GEMM C = A * B^T (bf16 A,B row-major, K contiguous) ----------------
// Round-3 structure: 128x128 tile, BK=32, 4 waves each 64x64 (4x4 of 16x16x32 MFMA).
// (6.3M LDS bank conflicts measured harmless at this size — latency slack absorbs them.)
// MODE 0: QKV fused via blockIdx.z. z==2 stores V transposed (Vt); z<2 applies RoPE in
//         the epilogue via an LDS fp32 exchange of the (d, d^64) partner halves.
// MODE 1: out-proj split-K over blockIdx.z (4 slices of 512): atomicAdd fp32 partials
//         into C (pre-initialized to the residual x), row-masked per partial.
template <int MODE>
__global__ __launch_bounds__(256) void gemm_bt(
    const u16t* __restrict__ A,
    const u16t* __restrict__ B0, const u16t* __restrict__ B1, const u16t* __restrict__ B2,
    void* __restrict__ C0, void* __restrict__ C1, void* __restrict__ C2,
    const float* __restrict__ cosb, const float* __restrict__ sinb,
    const int* __restrict__ am) {
  __shared__ u16t lds_all[2 * 128 * 32];   // 16 KB: A tile | B tile (reused by epilogue)
  u16t* Alds = lds_all;
  u16t* Blds = lds_all + 128 * 32;
  const int tid  = threadIdx.x;
  const int wave = tid >> 6;
  const int lane = tid & 63;
  const int m0 = blockIdx.y * 128;
  const int n0 = blockIdx.x * 128;
  const int z  = blockIdx.z;
  const u16t* B = (MODE == 0) ? (z == 0 ? B0 : (z == 1 ? B1 : B2)) : B0;
  const int kbeg = (MODE == 1) ? z * (DM / 4) : 0;
  const int kend = (MODE == 1) ? kbeg + (DM / 4) : DM;

  const f32x4 fzero = {0.f, 0.f, 0.f, 0.f};
  f32x4 acc[4][4];
#pragma unroll
  for (int i = 0; i < 4; ++i)
#pragma unroll
    for (int j = 0; j < 4; ++j) acc[i][j] = fzero;

  const int lr = lane >> 2;   // 0..15 row within 16-row chunk
  const int lc = lane & 3;    // 0..3  8-elem column chunk
  const int mw = (wave >> 1) * 64;
  const int nw = (wave & 1) * 64;
  const int quad = lane >> 4;
  const int c16  = lane & 15;

  for (int k0 = kbeg; k0 < kend; k0 += 32) {
    __syncthreads();
#pragma unroll
    for (int c = 0; c < 2; ++c) {
      const int ch = wave * 2 + c;        // 8 chunks of 1KB each per tile
      const int r  = ch * 16 + lr;
      async_copy16(A + (size_t)(m0 + r) * DM + k0 + lc * 8, Alds + ch * 512);
      async_copy16(B + (size_t)(n0 + r) * DM + k0 + lc * 8, Blds + ch * 512);
    }
    __syncthreads();
    short8 af[4], bfr[4];
#pragma unroll
    for (int mt = 0; mt < 4; ++mt)
      af[mt] = *(const short8*)(Alds + (mw + mt * 16 + c16) * 32 + quad * 8);
#pragma unroll
    for (int nt = 0; nt < 4; ++nt)
      bfr[nt] = *(const short8*)(Blds + (nw + nt * 16 + c16) * 32 + quad * 8);
#pragma unroll
    for (int mt = 0; mt < 4; ++mt)
#pragma unroll
      for (int nt = 0; nt < 4; ++nt)
        acc[mt][nt] = __builtin_amdgcn_mfma_f32_16x16x32_bf16(af[mt], bfr[nt], acc[mt][nt], 0, 0, 0);
  }

  if (MODE == 1) {
    // split-K: atomic fp32 accumulate into pre-initialized C (= x)
    float* C = (float*)C0;
#pragma unroll
    for (int mt = 0; mt < 4; ++mt) {
#pragma unroll
      for (int r = 0; r < 4; ++r) {
        const int row = m0 + mw + mt * 16 + quad * 4 + r;
        const float xmask = (am[row] != 0) ? 1.f : 0.f;
#pragma unroll
        for (int nt = 0; nt < 4; ++nt) {
          const int col = n0 + nw + nt * 16 + c16;
          atomicAdd(&C[(size_t)row * DM + col], acc[mt][nt][r] * xmask);
        }
      }
    }
  } else if (z == 2) {
    // V: store transposed
    u16t* C = (u16t*)C2;
#pragma unroll
    for (int mt = 0; mt < 4; ++mt)
#pragma unroll
      for (int r = 0; r < 4; ++r) {
        const int row = m0 + mw + mt * 16 + quad * 4 + r;
#pragma unroll
        for (int nt = 0; nt < 4; ++nt)
          C[(size_t)(n0 + nw + nt * 16 + c16) * TS + row] = f2bf(acc[mt][nt][r]);
      }
  } else {
    // Q/K: fused RoPE. Pair (d, d^64) lives in wave^1 (same mw, other nw) at the same
    // local (row, col) indices. Exchange fp32 acc through LDS, one mt-slice at a time.
    u16t* C = (u16t*)(z == 0 ? C0 : C1);
    float* ex = (float*)lds_all;   // 4 waves x 16 x 64 fp32 = 16 KB
#pragma unroll
    for (int mt = 0; mt < 4; ++mt) {
      __syncthreads();   // LDS region free (k-loop reads / previous slice reads done)
#pragma unroll
      for (int r = 0; r < 4; ++r)
#pragma unroll
        for (int nt = 0; nt < 4; ++nt)
          ex[wave * 1024 + (quad * 4 + r) * 64 + nt * 16 + c16] = acc[mt][nt][r];
      __syncthreads();
#pragma unroll
      for (int r = 0; r < 4; ++r) {
        const int row = m0 + mw + mt * 16 + quad * 4 + r;   // = t
#pragma unroll
        for (int nt = 0; nt < 4; ++nt) {
          const int col = n0 + nw + nt * 16 + c16;
          const int dh  = col & (DH - 1);
          const float x1 = acc[mt][nt][r];
          const float x2 = ex[(wave ^ 1) * 1024 + (quad * 4 + r) * 64 + nt * 16 + c16];
          const float c = cosb[row * DH + dh];
          const float s = sinb[row * DH + dh];
          const float vv = (dh < 64) ? (x1 * c - x2 * s) : (x1 * c + x2 * s);
          C[(size_t)row * DM + col] = f2bf(vv);
        }
      }
    }
  }
}

// ---------------- Flash attention (causal), LDS-staged K/V, 64-key tiles ----------------
__global__ __launch_bounds__(256) void attn_kernel(const u16t* __restrict__ Q,
                                                   const u16t* __restrict__ K,
                                                   const u16t* __restrict__ Vt,
                                                   const int* __restrict__ am,
                                                   u16t* __restrict__ O) {
  __shared__ u16t Klds[64 * 128];   // [key][d], swizzled granules, 16 KB
  __shared__ u16t Vlds[128 * 64];   // [d][key], swizzled granules, 16 KB
  __shared__ u16t Plds[4][1024];    // per-wave P: 2 chunks of 16x32, 8 KB
  const int wave = threadIdx.x >> 6;
  const int lane = threadIdx.x & 63;
  const int head = blockIdx.x & (NH - 1);
  const int qt   = (TS / 64 - 1) - (blockIdx.x >> 4);   // largest q-tiles first
  const int q0   = qt * 64 + wave * 16;
  const int quad = lane >> 4;
  const int c16  = lane & 15;
  const u16t* Qh  = Q + head * DH;
  const u16t* Kh  = K + head * DH;
  const u16t* Vth = Vt + (size_t)head * DH * TS;
  u16t* Pw = Plds[wave];

  short8 qf[4];
#pragma unroll
  for (int dc = 0; dc < 4; ++dc)
    qf[dc] = *(const short8*)(Qh + (size_t)(q0 + c16) * DM + dc * 32 + quad * 8);

  const f32x4 fzero = {0.f, 0.f, 0.f, 0.f};
  float m_run[4], l_run[4];
  f32x4 o_acc[8];
#pragma unroll
  for (int r = 0; r < 4; ++r) { m_run[r] = -1e30f; l_run[r] = 0.f; }
#pragma unroll
  for (int nt = 0; nt < 8; ++nt) o_acc[nt] = fzero;

  const float scale = 0.08838834764831845f;  // 1/sqrt(128)
  const int ntiles = qt + 1;

  for (int kt = 0; kt < ntiles; ++kt) {
    const int k0 = kt * 64;
    __syncthreads();   // all waves done reading previous K/V tile
#pragma unroll
    for (int c = 0; c < 4; ++c) {
      const int ch = wave * 4 + c;
      {  // K chunk: 4 rows x 16 granules
        const int r = 4 * ch + (lane >> 4);
        const int g = (lane & 15) ^ (r & 15);
        async_copy16(Kh + (size_t)(k0 + r) * DM + g * 8, Klds + ch * 512);
      }
      {  // V chunk: 8 rows x 8 granules
        const int r = 8 * ch + (lane >> 3);
        const int g = (lane & 7) ^ (r & 7);
        async_copy16(Vth + (size_t)r * TS + k0 + g * 8, Vlds + ch * 512);
      }
    }
    __syncthreads();   // drains vmcnt -> LDS tiles ready

    // S = Q K^T over 64 keys (4 groups of 16)
    f32x4 s[4];
#pragma unroll
    for (int ns = 0; ns < 4; ++ns) {
      f32x4 sa = fzero;
      const int rr = ns * 16 + c16;
#pragma unroll
      for (int dc = 0; dc < 4; ++dc) {
        const int g = dc * 4 + quad;
        short8 kf = *(const short8*)(Klds + rr * 128 + ((g ^ c16) * 8));
        sa = __builtin_amdgcn_mfma_f32_16x16x32_bf16(qf[dc], kf, sa, 0, 0, 0);
      }
      s[ns] = sa;
    }

    // mask + scale + online softmax
    float pv[4][4], tmax[4];
#pragma unroll
    for (int r = 0; r < 4; ++r) tmax[r] = -1e30f;
#pragma unroll
    for (int ns = 0; ns < 4; ++ns) {
      const int key = k0 + ns * 16 + c16;
      const bool kok = (am[key] != 0);
#pragma unroll
      for (int r = 0; r < 4; ++r) {
        const int qrow = q0 + quad * 4 + r;
        float v = s[ns][r] * scale;
        if (key > qrow || !kok) v = -1e30f;
        pv[ns][r] = v;
        tmax[r] = fmaxf(tmax[r], v);
      }
    }
#pragma unroll
    for (int off = 1; off < 16; off <<= 1)
#pragma unroll
      for (int r = 0; r < 4; ++r) tmax[r] = fmaxf(tmax[r], __shfl_xor(tmax[r], off, 64));
    float alpha[4], rsum[4];
#pragma unroll
    for (int r = 0; r < 4; ++r) {
      const float mn = fmaxf(m_run[r], tmax[r]);
      alpha[r] = __expf(m_run[r] - mn);
      m_run[r] = mn;
      float rs = 0.f;
#pragma unroll
      for (int ns = 0; ns < 4; ++ns) {
        const float e = __expf(pv[ns][r] - mn);
        pv[ns][r] = e;
        rs += e;
      }
      rsum[r] = rs;
    }
#pragma unroll
    for (int off = 1; off < 16; off <<= 1)
#pragma unroll
      for (int r = 0; r < 4; ++r) rsum[r] += __shfl_xor(rsum[r], off, 64);
#pragma unroll
    for (int r = 0; r < 4; ++r) l_run[r] = l_run[r] * alpha[r] + rsum[r];

    // P: C-layout -> LDS (two 16x32 chunks) -> A-layout
#pragma unroll
    for (int ns = 0; ns < 4; ++ns)
#pragma unroll
      for (int r = 0; r < 4; ++r)
        Pw[(ns >> 1) * 512 + (quad * 4 + r) * 32 + (ns & 1) * 16 + c16] = f2bf(pv[ns][r]);
    asm volatile("s_waitcnt lgkmcnt(0)" ::: "memory");
    short8 pf0 = *(const short8*)(Pw + c16 * 32 + quad * 8);
    short8 pf1 = *(const short8*)(Pw + 512 + c16 * 32 + quad * 8);

    // rescale O then accumulate P*V over 64 keys
#pragma unroll
    for (int nt = 0; nt < 8; ++nt)
#pragma unroll
      for (int r = 0; r < 4; ++r) o_acc[nt][r] *= alpha[r];
#pragma unroll
    for (int nt = 0; nt < 8; ++nt) {
      const int rr = nt * 16 + c16;
      short8 vf0 = *(const short8*)(Vlds + rr * 64 + ((quad ^ (c16 & 7)) * 8));
      o_acc[nt] = __builtin_amdgcn_mfma_f32_16x16x32_bf16(pf0, vf0, o_acc[nt], 0, 0, 0);
      short8 vf1 = *(const short8*)(Vlds + rr * 64 + (((4 + quad) ^ (c16 & 7)) * 8));
      o_acc[nt] = __builtin_amdgcn_mfma_f32_16x16x32_bf16(pf1, vf1, o_acc[nt], 0, 0, 0);
    }
  }

  // epilogue: O / l
#pragma unroll
  for (int r = 0; r < 4; ++r) {
    const float inv = 1.0f / fmaxf(l_run[r], 1e-20f);
    const int qrow = q0 + quad * 4 + r;
#pragma unroll
    for (int nt = 0; nt < 8; ++nt)
      O[(size_t)qrow * DM + head * DH + nt * 16 + c16] = f2bf(o_acc[nt][r] * inv);
  }
}

extern "C" void kernel_launch(void* const* d_in, const int* in_sizes, int n_in,
                              void* d_out, int out_size, void* d_ws, size_t ws_size,
                              hipStream_t stream) {
  const float* x    = (const float*)d_in[0];
  const float* cosb = (const float*)d_in[1];
  const float* sinb = (const float*)d_in[2];
  const int*   am   = (const int*)d_in[3];
  const float* lnw  = (const float*)d_in[4];
  const float* Wq   = (const float*)d_in[5];
  const float* Wk   = (const float*)d_in[6];
  const float* Wv   = (const float*)d_in[7];
  const float* Wo   = (const float*)d_in[8];
  float* out = (float*)d_out;

  u16t* h    = (u16t*)d_ws;                 // (T, D) bf16
  u16t* Q    = h + (size_t)TS * DM;         // (T, D)
  u16t* K    = Q + (size_t)TS * DM;         // (T, D)
  u16t* Vt   = K + (size_t)TS * DM;         // (D, T)  transposed V
  u16t* attn = Vt + (size_t)TS * DM;        // (T, D)
  u16t* Wb   = attn + (size_t)TS * DM;      // 4 x (D, D) bf16: q,k,v,o
  u16t* Wqb = Wb;
  u16t* Wkb = Wb + (size_t)DM * DM;
  u16t* Wvb = Wb + 2 * (size_t)DM * DM;
  u16t* Wob = Wb + 3 * (size_t)DM * DM;

  cast_weights<<<(4 * DM * DM / 4) / 256, 256, 0, stream>>>(Wq, Wk, Wv, Wo, Wb);
  rmsnorm_kernel<<<TS, 256, 0, stream>>>(x, lnw, h);
  // QKV with fused RoPE (z<2) and transposed-V store (z==2)
  gemm_bt<0><<<dim3(16, 16, 3), 256, 0, stream>>>(h, Wqb, Wkb, Wvb, Q, K, Vt, cosb, sinb, am);
  attn_kernel<<<NH * (TS / 64), 256, 0, stream>>>(Q, K, Vt, am, attn);
  // out = x; then split-K out-proj accumulates mask * (attn @ Wo^T) atomically
  hipMemcpyAsync(out, x, (size_t)TS * DM * sizeof(float), hipMemcpyDeviceToDevice, stream);
  gemm_bt<1><<<dim3(16, 16, 4), 256, 0, stream>>>(attn, Wob, nullptr, nullptr, out, nullptr, nullptr, nullptr, nullptr, am);
}

// Round 6
// 354.063 us; speedup vs baseline: 1.1674x; 1.1674x over previous
//
#include <hip/hip_runtime.h>
#include <stdint.h>

#define TS 2048
#define DM 2048
#define NH 16
#define DH 128

typedef unsigned short u16t;
typedef __attribute__((ext_vector_type(8))) short short8;
typedef __attribute__((ext_vector_type(4))) float f32x4;
typedef __attribute__((ext_vector_type(4))) unsigned int u32x4;

__device__ __forceinline__ float bf2f(u16t b) {
  return __uint_as_float(((unsigned int)b) << 16);
}
__device__ __forceinline__ u16t f2bf(float f) {
  unsigned int u = __float_as_uint(f);
  u += 0x7FFFu + ((u >> 16) & 1u);   // round-to-nearest-even
  return (u16t)(u >> 16);
}

// async global->LDS, 16B per lane. LDS dest = wave-uniform base + lane*16.
__device__ __forceinline__ void async_copy16(const u16t* g, u16t* l) {
  __builtin_amdgcn_global_load_lds((const __attribute__((address_space(1))) void*)g,
                                   (__attribute__((address_space(3))) void*)l, 16, 0, 0);
}

// ---------------- fp32 weights -> bf16 (4 matrices, ws) ----------------
__global__ __launch_bounds__(256) void cast_weights(const float* __restrict__ W0,
                                                    const float* __restrict__ W1,
                                                    const float* __restrict__ W2,
                                                    const float* __restrict__ W3,
                                                    u16t* __restrict__ out) {
  const int idx = blockIdx.x * 256 + threadIdx.x;   // 4M threads, 4 elems each
  const int mat = idx >> 20;
  const size_t off = (size_t)(idx & 0xFFFFF) * 4;
  const float* W = (mat == 0) ? W0 : (mat == 1) ? W1 : (mat == 2) ? W2 : W3;
  const f32x4 v = *(const f32x4*)(W + off);
  union { u16t s[4]; uint64_t u; } o;
#pragma unroll
  for (int i = 0; i < 4; ++i) o.s[i] = f2bf(v[i]);
  *(uint64_t*)(out + (size_t)mat * (DM * DM) + off) = o.u;
}

// ---------------- RMSNorm: h = bf16( ln_w * x * rsqrt(mean(x^2)+eps) ) ----------------
__global__ __launch_bounds__(256) void rmsnorm_kernel(const float* __restrict__ x,
                                                      const float* __restrict__ w,
                                                      u16t* __restrict__ h) {
  const int row = blockIdx.x;
  const int tid = threadIdx.x;
  const float* xr = x + (size_t)row * DM + tid * 8;
  f32x4 v0 = *(const f32x4*)(xr);
  f32x4 v1 = *(const f32x4*)(xr + 4);
  float f[8];
#pragma unroll
  for (int i = 0; i < 4; ++i) { f[i] = v0[i]; f[i + 4] = v1[i]; }
  float ss = 0.f;
#pragma unroll
  for (int i = 0; i < 8; ++i) ss += f[i] * f[i];
#pragma unroll
  for (int off = 1; off < 64; off <<= 1) ss += __shfl_xor(ss, off, 64);
  __shared__ float wsum[4];
  if ((tid & 63) == 0) wsum[tid >> 6] = ss;
  __syncthreads();
  float tot = wsum[0] + wsum[1] + wsum[2] + wsum[3];
  float rs = rsqrtf(tot * (1.0f / DM) + 1e-5f);
  f32x4 w0 = *(const f32x4*)(w + tid * 8);
  f32x4 w1 = *(const f32x4*)(w + tid * 8 + 4);
  u32x4 o;
#pragma unroll
  for (int i = 0; i < 4; ++i) {
    unsigned int lo = f2bf(f[2 * i]     * ((2 * i     < 4) ? w0[2 * i]     : w1[2 * i - 4]) * rs);
    unsigned int hi = f2bf(f[2 * i + 1] * ((2 * i + 1 < 4) ? w0[2 * i + 1] : w1[2 * i - 3]) * rs);
    o[i] = lo | (hi << 16);
  }
  *(u32x4*)(h + (size_t)row * DM + tid * 8) = o;
}

// ---------------- GEMM C = A * B^T (bf16 A,B row-major, K contiguous) ----------------
// Round-3 structure: 128x128 tile, BK=32, 4 waves each 64x64 (4x4 of 16x16x32 MFMA).
// 6.3M LDS bank conflicts measured harmless here (r4: removing them cost 10 us);
// epilogue fusions measured harmful (r5). Keep it plain.
// MODE 0: QKV fused via blockIdx.z (z==2 stores transposed for Vt); bf16 C.
// MODE 1: out-proj: C(fp32) = xres + (am ? A*B^T : 0)
template <int MODE>
__global__ __launch_bounds__(256) void gemm_bt(
    const u16t* __restrict__ A,
    const u16t* __restrict__ B0, const u16t* __restrict__ B1, const u16t* __restrict__ B2,
    void* __restrict__ C0, void* __restrict__ C1, void* __restrict__ C2,
    const float* __restrict__ xres, const int* __restrict__ am) {
  __shared__ u16t Alds[128 * 32];
  __shared__ u16t Blds[128 * 32];
  const int tid  = threadIdx.x;
  const int wave = tid >> 6;
  const int lane = tid & 63;
  const int m0 = blockIdx.y * 128;
  const int n0 = blockIdx.x * 128;
  const int z  = blockIdx.z;
  const u16t* B = (MODE == 0) ? (z == 0 ? B0 : (z == 1 ? B1 : B2)) : B0;

  const f32x4 fzero = {0.f, 0.f, 0.f, 0.f};
  f32x4 acc[4][4];
#pragma unroll
  for (int i = 0; i < 4; ++i)
#pragma unroll
    for (int j = 0; j < 4; ++j) acc[i][j] = fzero;

  const int lr = lane >> 2;   // 0..15 row within 16-row chunk
  const int lc = lane & 3;    // 0..3  8-elem column chunk
  const int mw = (wave >> 1) * 64;
  const int nw = (wave & 1) * 64;
  const int quad = lane >> 4;
  const int c16  = lane & 15;

  for (int k0 = 0; k0 < DM; k0 += 32) {
    __syncthreads();
#pragma unroll
    for (int c = 0; c < 2; ++c) {
      const int ch = wave * 2 + c;        // 8 chunks of 1KB each per tile
      const int r  = ch * 16 + lr;
      async_copy16(A + (size_t)(m0 + r) * DM + k0 + lc * 8, Alds + ch * 512);
      async_copy16(B + (size_t)(n0 + r) * DM + k0 + lc * 8, Blds + ch * 512);
    }
    __syncthreads();
    short8 af[4], bfr[4];
#pragma unroll
    for (int mt = 0; mt < 4; ++mt)
      af[mt] = *(const short8*)(Alds + (mw + mt * 16 + c16) * 32 + quad * 8);
#pragma unroll
    for (int nt = 0; nt < 4; ++nt)
      bfr[nt] = *(const short8*)(Blds + (nw + nt * 16 + c16) * 32 + quad * 8);
#pragma unroll
    for (int mt = 0; mt < 4; ++mt)
#pragma unroll
      for (int nt = 0; nt < 4; ++nt)
        acc[mt][nt] = __builtin_amdgcn_mfma_f32_16x16x32_bf16(af[mt], bfr[nt], acc[mt][nt], 0, 0, 0);
  }

#pragma unroll
  for (int mt = 0; mt < 4; ++mt) {
#pragma unroll
    for (int r = 0; r < 4; ++r) {
      const int row = m0 + mw + mt * 16 + quad * 4 + r;
      float xmask = 1.f;
      if (MODE == 1) xmask = (am[row] != 0) ? 1.f : 0.f;
#pragma unroll
      for (int nt = 0; nt < 4; ++nt) {
        const int col = n0 + nw + nt * 16 + c16;
        float vv = acc[mt][nt][r];
        if (MODE == 1) {
          float* C = (float*)C0;
          C[(size_t)row * DM + col] = vv * xmask + xres[(size_t)row * DM + col];
        } else {
          u16t* C = (u16t*)(z == 0 ? C0 : (z == 1 ? C1 : C2));
          if (z == 2) C[(size_t)col * TS + row] = f2bf(vv);   // Vt[d_global][t]
          else        C[(size_t)row * DM + col] = f2bf(vv);
        }
      }
    }
  }
}

// ---------------- RoPE in-place on Q and K (bf16), fp32 cos/sin ----------------
__global__ __launch_bounds__(256) void rope_kernel(u16t* __restrict__ Q, u16t* __restrict__ K,
                                                   const float* __restrict__ cosb,
                                                   const float* __restrict__ sinb) {
  int idx = blockIdx.x * 256 + threadIdx.x;   // 2 * 2048 * 1024 threads
  int mat = idx >> 21;
  int rem = idx & ((1 << 21) - 1);
  int t = rem >> 10;
  int p = rem & 1023;
  int head = p >> 6, d = p & 63;
  u16t* M = mat ? K : Q;
  size_t base = (size_t)t * DM + head * DH + d;
  float c = cosb[t * DH + d];
  float s = sinb[t * DH + d];
  float x1 = bf2f(M[base]);
  float x2 = bf2f(M[base + 64]);
  M[base]      = f2bf(x1 * c - x2 * s);
  M[base + 64] = f2bf(x2 * c + x1 * s);
}

// ---------------- Flash attention (causal), double-buffered LDS K/V ----------------
// One barrier per k-tile: prefetch tile kt+1 into buf nxt, compute tile kt on buf cur,
// then a single __syncthreads() both drains the prefetch (vmcnt0) and protects cur
// from overwrite. Loads overlap the whole QK->softmax->PV window.
__global__ __launch_bounds__(256) void attn_kernel(const u16t* __restrict__ Q,
                                                   const u16t* __restrict__ K,
                                                   const u16t* __restrict__ Vt,
                                                   const int* __restrict__ am,
                                                   u16t* __restrict__ O) {
  __shared__ u16t Klds[2][64 * 128];   // [key][d], swizzled granules, 2x16 KB
  __shared__ u16t Vlds[2][128 * 64];   // [d][key], swizzled granules, 2x16 KB
  __shared__ u16t Plds[4][1024];       // per-wave P: 2 chunks of 16x32, 8 KB
  const int wave = threadIdx.x >> 6;
  const int lane = threadIdx.x & 63;
  const int head = blockIdx.x & (NH - 1);
  const int qt   = (TS / 64 - 1) - (blockIdx.x >> 4);   // largest q-tiles first
  const int q0   = qt * 64 + wave * 16;
  const int quad = lane >> 4;
  const int c16  = lane & 15;
  const u16t* Qh  = Q + head * DH;
  const u16t* Kh  = K + head * DH;
  const u16t* Vth = Vt + (size_t)head * DH * TS;
  u16t* Pw = Plds[wave];

  // staging lane constants
  const int krow_s = (lane >> 4);                 // 0..3 row-in-chunk (K)
  const int kg_s   = (lane & 15);
  const int vrow_s = (lane >> 3);                 // 0..7 row-in-chunk (V)
  const int vg_s   = (lane & 7);

  short8 qf[4];
#pragma unroll
  for (int dc = 0; dc < 4; ++dc)
    qf[dc] = *(const short8*)(Qh + (size_t)(q0 + c16) * DM + dc * 32 + quad * 8);

  const f32x4 fzero = {0.f, 0.f, 0.f, 0.f};
  float m_run[4], l_run[4];
  f32x4 o_acc[8];
#pragma unroll
  for (int r = 0; r < 4; ++r) { m_run[r] = -1e30f; l_run[r] = 0.f; }
#pragma unroll
  for (int nt = 0; nt < 8; ++nt) o_acc[nt] = fzero;

  const float scale = 0.08838834764831845f;  // 1/sqrt(128)
  const int ntiles = qt + 1;

  // prologue: stage tile 0 into buffer 0
#pragma unroll
  for (int c = 0; c < 4; ++c) {
    const int ch = wave * 4 + c;
    { const int r = 4 * ch + krow_s;
      async_copy16(Kh + (size_t)r * DM + (kg_s ^ (r & 15)) * 8, Klds[0] + ch * 512); }
    { const int r = 8 * ch + vrow_s;
      async_copy16(Vth + (size_t)r * TS + (vg_s ^ (r & 7)) * 8, Vlds[0] + ch * 512); }
  }
  __syncthreads();   // drain prologue loads

  for (int kt = 0; kt < ntiles; ++kt) {
    const int cur = kt & 1;
    const int k0 = kt * 64;
    // prefetch next tile into the other buffer (overlaps with compute below)
    if (kt + 1 < ntiles) {
      const int kn = k0 + 64;
#pragma unroll
      for (int c = 0; c < 4; ++c) {
        const int ch = wave * 4 + c;
        { const int r = 4 * ch + krow_s;
          async_copy16(Kh + (size_t)(kn + r) * DM + (kg_s ^ (r & 15)) * 8, Klds[cur ^ 1] + ch * 512); }
        { const int r = 8 * ch + vrow_s;
          async_copy16(Vth + (size_t)r * TS + kn + (vg_s ^ (r & 7)) * 8, Vlds[cur ^ 1] + ch * 512); }
      }
    }

    // S = Q K^T over 64 keys (4 groups of 16)
    f32x4 s[4];
#pragma unroll
    for (int ns = 0; ns < 4; ++ns) {
      f32x4 sa = fzero;
      const int rr = ns * 16 + c16;
#pragma unroll
      for (int dc = 0; dc < 4; ++dc) {
        const int g = dc * 4 + quad;
        short8 kf = *(const short8*)(Klds[cur] + rr * 128 + ((g ^ c16) * 8));
        sa = __builtin_amdgcn_mfma_f32_16x16x32_bf16(qf[dc], kf, sa, 0, 0, 0);
      }
      s[ns] = sa;
    }

    // mask + scale + online softmax
    float pv[4][4], tmax[4];
#pragma unroll
    for (int r = 0; r < 4; ++r) tmax[r] = -1e30f;
#pragma unroll
    for (int ns = 0; ns < 4; ++ns) {
      const int key = k0 + ns * 16 + c16;
      const bool kok = (am[key] != 0);
#pragma unroll
      for (int r = 0; r < 4; ++r) {
        const int qrow = q0 + quad * 4 + r;
        float v = s[ns][r] * scale;
        if (key > qrow || !kok) v = -1e30f;
        pv[ns][r] = v;
        tmax[r] = fmaxf(tmax[r], v);
      }
    }
#pragma unroll
    for (int off = 1; off < 16; off <<= 1)
#pragma unroll
      for (int r = 0; r < 4; ++r) tmax[r] = fmaxf(tmax[r], __shfl_xor(tmax[r], off, 64));
    float alpha[4], rsum[4];
#pragma unroll
    for (int r = 0; r < 4; ++r) {
      const float mn = fmaxf(m_run[r], tmax[r]);
      alpha[r] = __expf(m_run[r] - mn);
      m_run[r] = mn;
      float rs = 0.f;
#pragma unroll
      for (int ns = 0; ns < 4; ++ns) {
        const float e = __expf(pv[ns][r] - mn);
        pv[ns][r] = e;
        rs += e;
      }
      rsum[r] = rs;
    }
#pragma unroll
    for (int off = 1; off < 16; off <<= 1)
#pragma unroll
      for (int r = 0; r < 4; ++r) rsum[r] += __shfl_xor(rsum[r], off, 64);
#pragma unroll
    for (int r = 0; r < 4; ++r) l_run[r] = l_run[r] * alpha[r] + rsum[r];

    // P: C-layout -> LDS (two 16x32 chunks) -> A-layout
#pragma unroll
    for (int ns = 0; ns < 4; ++ns)
#pragma unroll
      for (int r = 0; r < 4; ++r)
        Pw[(ns >> 1) * 512 + (quad * 4 + r) * 32 + (ns & 1) * 16 + c16] = f2bf(pv[ns][r]);
    asm volatile("s_waitcnt lgkmcnt(0)" ::: "memory");
    short8 pf0 = *(const short8*)(Pw + c16 * 32 + quad * 8);
    short8 pf1 = *(const short8*)(Pw + 512 + c16 * 32 + quad * 8);

    // rescale O then accumulate P*V over 64 keys
#pragma unroll
    for (int nt = 0; nt < 8; ++nt)
#pragma unroll
      for (int r = 0; r < 4; ++r) o_acc[nt][r] *= alpha[r];
#pragma unroll
    for (int nt = 0; nt < 8; ++nt) {
      const int rr = nt * 16 + c16;
      short8 vf0 = *(const short8*)(Vlds[cur] + rr * 64 + ((quad ^ (c16 & 7)) * 8));
      o_acc[nt] = __builtin_amdgcn_mfma_f32_16x16x32_bf16(pf0, vf0, o_acc[nt], 0, 0, 0);
      short8 vf1 = *(const short8*)(Vlds[cur] + rr * 64 + (((4 + quad) ^ (c16 & 7)) * 8));
      o_acc[nt] = __builtin_amdgcn_mfma_f32_16x16x32_bf16(pf1, vf1, o_acc[nt], 0, 0, 0);
    }

    __syncthreads();   // drains prefetch vmcnt + all waves done reading cur
  }

  // epilogue: O / l
#pragma unroll
  for (int r = 0; r < 4; ++r) {
    const float inv = 1.0f / fmaxf(l_run[r], 1e-20f);
    const int qrow = q0 + quad * 4 + r;
#pragma unroll
    for (int nt = 0; nt < 8; ++nt)
      O[(size_t)qrow * DM + head * DH + nt * 16 + c16] = f2bf(o_acc[nt][r] * inv);
  }
}

extern "C" void kernel_launch(void* const* d_in, const int* in_sizes, int n_in,
                              void* d_out, int out_size, void* d_ws, size_t ws_size,
                              hipStream_t stream) {
  const float* x    = (const float*)d_in[0];
  const float* cosb = (const float*)d_in[1];
  const float* sinb = (const float*)d_in[2];
  const int*   am   = (const int*)d_in[3];
  const float* lnw  = (const float*)d_in[4];
  const float* Wq   = (const float*)d_in[5];
  const float* Wk   = (const float*)d_in[6];
  const float* Wv   = (const float*)d_in[7];
  const float* Wo   = (const float*)d_in[8];
  float* out = (float*)d_out;

  u16t* h    = (u16t*)d_ws;                 // (T, D) bf16
  u16t* Q    = h + (size_t)TS * DM;         // (T, D)
  u16t* K    = Q + (size_t)TS * DM;         // (T, D)
  u16t* Vt   = K + (size_t)TS * DM;         // (D, T)  transposed V
  u16t* attn = Vt + (size_t)TS * DM;        // (T, D)
  u16t* Wb   = attn + (size_t)TS * DM;      // 4 x (D, D) bf16: q,k,v,o
  u16t* Wqb = Wb;
  u16t* Wkb = Wb + (size_t)DM * DM;
  u16t* Wvb = Wb + 2 * (size_t)DM * DM;
  u16t* Wob = Wb + 3 * (size_t)DM * DM;

  cast_weights<<<(4 * DM * DM / 4) / 256, 256, 0, stream>>>(Wq, Wk, Wv, Wo, Wb);
  rmsnorm_kernel<<<TS, 256, 0, stream>>>(x, lnw, h);
  gemm_bt<0><<<dim3(16, 16, 3), 256, 0, stream>>>(h, Wqb, Wkb, Wvb, Q, K, Vt, nullptr, nullptr);
  rope_kernel<<<(2 * TS * 1024) / 256, 256, 0, stream>>>(Q, K, cosb, sinb);
  attn_kernel<<<NH * (TS / 64), 256, 0, stream>>>(Q, K, Vt, am, attn);
  gemm_bt<1><<<dim3(16, 16, 1), 256, 0, stream>>>(attn, Wob, nullptr, nullptr, out, nullptr, nullptr, x, am);
}

// Round 7
// 332.675 us; speedup vs baseline: 1.2424x; 1.0643x over previous
//
#include <hip/hip_runtime.h>
#include <stdint.h>

#define TS 2048
#define DM 2048
#define NH 16
#define DH 128

typedef unsigned short u16t;
typedef __attribute__((ext_vector_type(8))) short short8;
typedef __attribute__((ext_vector_type(4))) float f32x4;
typedef __attribute__((ext_vector_type(4))) unsigned int u32x4;

__device__ __forceinline__ float bf2f(u16t b) {
  return __uint_as_float(((unsigned int)b) << 16);
}
__device__ __forceinline__ u16t f2bf(float f) {
  unsigned int u = __float_as_uint(f);
  u += 0x7FFFu + ((u >> 16) & 1u);   // round-to-nearest-even
  return (u16t)(u >> 16);
}

// async global->LDS, 16B per lane. LDS dest = wave-uniform base + lane*16.
__device__ __forceinline__ void async_copy16(const u16t* g, u16t* l) {
  __builtin_amdgcn_global_load_lds((const __attribute__((address_space(1))) void*)g,
                                   (__attribute__((address_space(3))) void*)l, 16, 0, 0);
}

// DPP row_ror within 16-lane rows: pure-VALU cross-lane (vs ds_bpermute for __shfl).
#define DPP_ROR_F(x, n) __uint_as_float(__builtin_amdgcn_update_dpp( \
    0, (int)__float_as_uint(x), 0x120 | (n), 0xF, 0xF, true))

__device__ __forceinline__ float row16_max(float x) {
  x = fmaxf(x, DPP_ROR_F(x, 8));
  x = fmaxf(x, DPP_ROR_F(x, 4));
  x = fmaxf(x, DPP_ROR_F(x, 2));
  x = fmaxf(x, DPP_ROR_F(x, 1));
  return x;
}
__device__ __forceinline__ float row16_sum(float x) {
  x += DPP_ROR_F(x, 8);
  x += DPP_ROR_F(x, 4);
  x += DPP_ROR_F(x, 2);
  x += DPP_ROR_F(x, 1);
  return x;
}

// ---------------- fp32 weights -> bf16 (4 matrices, ws) ----------------
__global__ __launch_bounds__(256) void cast_weights(const float* __restrict__ W0,
                                                    const float* __restrict__ W1,
                                                    const float* __restrict__ W2,
                                                    const float* __restrict__ W3,
                                                    u16t* __restrict__ out) {
  const int idx = blockIdx.x * 256 + threadIdx.x;   // 4M threads, 4 elems each
  const int mat = idx >> 20;
  const size_t off = (size_t)(idx & 0xFFFFF) * 4;
  const float* W = (mat == 0) ? W0 : (mat == 1) ? W1 : (mat == 2) ? W2 : W3;
  const f32x4 v = *(const f32x4*)(W + off);
  union { u16t s[4]; uint64_t u; } o;
#pragma unroll
  for (int i = 0; i < 4; ++i) o.s[i] = f2bf(v[i]);
  *(uint64_t*)(out + (size_t)mat * (DM * DM) + off) = o.u;
}

// ---------------- RMSNorm: h = bf16( ln_w * x * rsqrt(mean(x^2)+eps) ) ----------------
__global__ __launch_bounds__(256) void rmsnorm_kernel(const float* __restrict__ x,
                                                      const float* __restrict__ w,
                                                      u16t* __restrict__ h) {
  const int row = blockIdx.x;
  const int tid = threadIdx.x;
  const float* xr = x + (size_t)row * DM + tid * 8;
  f32x4 v0 = *(const f32x4*)(xr);
  f32x4 v1 = *(const f32x4*)(xr + 4);
  float f[8];
#pragma unroll
  for (int i = 0; i < 4; ++i) { f[i] = v0[i]; f[i + 4] = v1[i]; }
  float ss = 0.f;
#pragma unroll
  for (int i = 0; i < 8; ++i) ss += f[i] * f[i];
#pragma unroll
  for (int off = 1; off < 64; off <<= 1) ss += __shfl_xor(ss, off, 64);
  __shared__ float wsum[4];
  if ((tid & 63) == 0) wsum[tid >> 6] = ss;
  __syncthreads();
  float tot = wsum[0] + wsum[1] + wsum[2] + wsum[3];
  float rs = rsqrtf(tot * (1.0f / DM) + 1e-5f);
  f32x4 w0 = *(const f32x4*)(w + tid * 8);
  f32x4 w1 = *(const f32x4*)(w + tid * 8 + 4);
  u32x4 o;
#pragma unroll
  for (int i = 0; i < 4; ++i) {
    unsigned int lo = f2bf(f[2 * i]     * ((2 * i     < 4) ? w0[2 * i]     : w1[2 * i - 4]) * rs);
    unsigned int hi = f2bf(f[2 * i + 1] * ((2 * i + 1 < 4) ? w0[2 * i + 1] : w1[2 * i - 3]) * rs);
    o[i] = lo | (hi << 16);
  }
  *(u32x4*)(h + (size_t)row * DM + tid * 8) = o;
}

// ---------------- GEMM C = A * B^T (bf16 A,B row-major, K contiguous) ----------------
// Round-3 structure: 128x128 tile, BK=32, 4 waves each 64x64 (4x4 of 16x16x32 MFMA).
// 6.3M LDS bank conflicts measured harmless (r4); epilogue fusions measured harmful (r5).
// MODE 0: QKV fused via blockIdx.z (z==2 stores transposed for Vt); bf16 C.
// MODE 1: out-proj: C(fp32) = xres + (am ? A*B^T : 0)
template <int MODE>
__global__ __launch_bounds__(256) void gemm_bt(
    const u16t* __restrict__ A,
    const u16t* __restrict__ B0, const u16t* __restrict__ B1, const u16t* __restrict__ B2,
    void* __restrict__ C0, void* __restrict__ C1, void* __restrict__ C2,
    const float* __restrict__ xres, const int* __restrict__ am) {
  __shared__ u16t Alds[128 * 32];
  __shared__ u16t Blds[128 * 32];
  const int tid  = threadIdx.x;
  const int wave = tid >> 6;
  const int lane = tid & 63;
  const int m0 = blockIdx.y * 128;
  const int n0 = blockIdx.x * 128;
  const int z  = blockIdx.z;
  const u16t* B = (MODE == 0) ? (z == 0 ? B0 : (z == 1 ? B1 : B2)) : B0;

  const f32x4 fzero = {0.f, 0.f, 0.f, 0.f};
  f32x4 acc[4][4];
#pragma unroll
  for (int i = 0; i < 4; ++i)
#pragma unroll
    for (int j = 0; j < 4; ++j) acc[i][j] = fzero;

  const int lr = lane >> 2;   // 0..15 row within 16-row chunk
  const int lc = lane & 3;    // 0..3  8-elem column chunk
  const int mw = (wave >> 1) * 64;
  const int nw = (wave & 1) * 64;
  const int quad = lane >> 4;
  const int c16  = lane & 15;

  for (int k0 = 0; k0 < DM; k0 += 32) {
    __syncthreads();
#pragma unroll
    for (int c = 0; c < 2; ++c) {
      const int ch = wave * 2 + c;        // 8 chunks of 1KB each per tile
      const int r  = ch * 16 + lr;
      async_copy16(A + (size_t)(m0 + r) * DM + k0 + lc * 8, Alds + ch * 512);
      async_copy16(B + (size_t)(n0 + r) * DM + k0 + lc * 8, Blds + ch * 512);
    }
    __syncthreads();
    short8 af[4], bfr[4];
#pragma unroll
    for (int mt = 0; mt < 4; ++mt)
      af[mt] = *(const short8*)(Alds + (mw + mt * 16 + c16) * 32 + quad * 8);
#pragma unroll
    for (int nt = 0; nt < 4; ++nt)
      bfr[nt] = *(const short8*)(Blds + (nw + nt * 16 + c16) * 32 + quad * 8);
#pragma unroll
    for (int mt = 0; mt < 4; ++mt)
#pragma unroll
      for (int nt = 0; nt < 4; ++nt)
        acc[mt][nt] = __builtin_amdgcn_mfma_f32_16x16x32_bf16(af[mt], bfr[nt], acc[mt][nt], 0, 0, 0);
  }

#pragma unroll
  for (int mt = 0; mt < 4; ++mt) {
#pragma unroll
    for (int r = 0; r < 4; ++r) {
      const int row = m0 + mw + mt * 16 + quad * 4 + r;
      float xmask = 1.f;
      if (MODE == 1) xmask = (am[row] != 0) ? 1.f : 0.f;
#pragma unroll
      for (int nt = 0; nt < 4; ++nt) {
        const int col = n0 + nw + nt * 16 + c16;
        float vv = acc[mt][nt][r];
        if (MODE == 1) {
          float* C = (float*)C0;
          C[(size_t)row * DM + col] = vv * xmask + xres[(size_t)row * DM + col];
        } else {
          u16t* C = (u16t*)(z == 0 ? C0 : (z == 1 ? C1 : C2));
          if (z == 2) C[(size_t)col * TS + row] = f2bf(vv);   // Vt[d_global][t]
          else        C[(size_t)row * DM + col] = f2bf(vv);
        }
      }
    }
  }
}

// ---------------- RoPE in-place on Q and K (bf16), fp32 cos/sin ----------------
__global__ __launch_bounds__(256) void rope_kernel(u16t* __restrict__ Q, u16t* __restrict__ K,
                                                   const float* __restrict__ cosb,
                                                   const float* __restrict__ sinb) {
  int idx = blockIdx.x * 256 + threadIdx.x;   // 2 * 2048 * 1024 threads
  int mat = idx >> 21;
  int rem = idx & ((1 << 21) - 1);
  int t = rem >> 10;
  int p = rem & 1023;
  int head = p >> 6, d = p & 63;
  u16t* M = mat ? K : Q;
  size_t base = (size_t)t * DM + head * DH + d;
  float c = cosb[t * DH + d];
  float s = sinb[t * DH + d];
  float x1 = bf2f(M[base]);
  float x2 = bf2f(M[base + 64]);
  M[base]      = f2bf(x1 * c - x2 * s);
  M[base + 64] = f2bf(x2 * c + x1 * s);
}

// ---------------- Flash attention (causal), LDS-staged K/V, 128-key tiles ----------------
// Per-iteration critical path trimmed: softmax reductions via DPP row_ror (pure VALU,
// no ds_bpermute), 128-key tiles halve barrier+softmax rounds. Single-buffered
// (dbuf measured neutral r6). LDS 80 KB -> 2 blocks/CU.
__global__ __launch_bounds__(256) void attn_kernel(const u16t* __restrict__ Q,
                                                   const u16t* __restrict__ K,
                                                   const u16t* __restrict__ Vt,
                                                   const int* __restrict__ am,
                                                   u16t* __restrict__ O) {
  __shared__ u16t Klds[128 * 128];   // [key][d], swizzled granules, 32 KB
  __shared__ u16t Vlds[128 * 128];   // [d][key], swizzled granules, 32 KB
  __shared__ u16t Plds[4][2048];     // per-wave P: 4 chunks of 16x32, 16 KB
  const int wave = threadIdx.x >> 6;
  const int lane = threadIdx.x & 63;
  const int head = blockIdx.x & (NH - 1);
  const int qt   = (TS / 64 - 1) - (blockIdx.x >> 4);   // largest q-tiles first
  const int q0   = qt * 64 + wave * 16;
  const int quad = lane >> 4;
  const int c16  = lane & 15;
  const u16t* Qh  = Q + head * DH;
  const u16t* Kh  = K + head * DH;
  const u16t* Vth = Vt + (size_t)head * DH * TS;
  u16t* Pw = Plds[wave];

  // staging lane constants: chunk = 4 rows x 16 granules (16B each)
  const int row_s = (lane >> 4);    // 0..3 row within chunk
  const int g_s   = (lane & 15);    // granule slot

  short8 qf[4];
#pragma unroll
  for (int dc = 0; dc < 4; ++dc)
    qf[dc] = *(const short8*)(Qh + (size_t)(q0 + c16) * DM + dc * 32 + quad * 8);

  const f32x4 fzero = {0.f, 0.f, 0.f, 0.f};
  float m_run[4], l_run[4];
  f32x4 o_acc[8];
#pragma unroll
  for (int r = 0; r < 4; ++r) { m_run[r] = -1e30f; l_run[r] = 0.f; }
#pragma unroll
  for (int nt = 0; nt < 8; ++nt) o_acc[nt] = fzero;

  const float scale = 0.08838834764831845f;  // 1/sqrt(128)
  const int ntiles = (qt * 64 + 191) >> 7;   // 128-wide tiles covering keys 0..q0+63

  for (int kt = 0; kt < ntiles; ++kt) {
    const int k0 = kt * 128;
    __syncthreads();   // all waves done reading previous K/V tile
    // stage K (32 chunks of 1KB) + V (32 chunks): 8+8 per wave
#pragma unroll
    for (int c = 0; c < 8; ++c) {
      const int ch = wave * 8 + c;
      const int r  = 4 * ch + row_s;           // 0..127
      const int g  = g_s ^ (r & 15);
      async_copy16(Kh + (size_t)(k0 + r) * DM + g * 8, Klds + ch * 512);
      async_copy16(Vth + (size_t)r * TS + k0 + g * 8, Vlds + ch * 512);
    }
    __syncthreads();   // drains vmcnt -> LDS tiles ready

    // S = Q K^T over 128 keys (8 groups of 16)
    f32x4 s[8];
#pragma unroll
    for (int ns = 0; ns < 8; ++ns) {
      f32x4 sa = fzero;
      const int rr = ns * 16 + c16;
#pragma unroll
      for (int dc = 0; dc < 4; ++dc) {
        short8 kf = *(const short8*)(Klds + rr * 128 + (((dc * 4 + quad) ^ c16) * 8));
        sa = __builtin_amdgcn_mfma_f32_16x16x32_bf16(qf[dc], kf, sa, 0, 0, 0);
      }
      s[ns] = sa;
    }

    // mask + scale + online softmax (DPP rotate-reduce within each 16-lane row)
    float pv[8][4], tmax[4];
#pragma unroll
    for (int r = 0; r < 4; ++r) tmax[r] = -1e30f;
#pragma unroll
    for (int ns = 0; ns < 8; ++ns) {
      const int key = k0 + ns * 16 + c16;
      const bool kok = (am[key] != 0);
#pragma unroll
      for (int r = 0; r < 4; ++r) {
        const int qrow = q0 + quad * 4 + r;
        float v = s[ns][r] * scale;
        if (key > qrow || !kok) v = -1e30f;
        pv[ns][r] = v;
        tmax[r] = fmaxf(tmax[r], v);
      }
    }
    float alpha[4], rsum[4];
#pragma unroll
    for (int r = 0; r < 4; ++r) {
      const float mn = fmaxf(m_run[r], row16_max(tmax[r]));
      alpha[r] = __expf(m_run[r] - mn);
      m_run[r] = mn;
      float rs = 0.f;
#pragma unroll
      for (int ns = 0; ns < 8; ++ns) {
        const float e = __expf(pv[ns][r] - mn);
        pv[ns][r] = e;
        rs += e;
      }
      rsum[r] = row16_sum(rs);
      l_run[r] = l_run[r] * alpha[r] + rsum[r];
    }

    // P: C-layout -> LDS (four 16x32 chunks) -> A-layout
#pragma unroll
    for (int ns = 0; ns < 8; ++ns)
#pragma unroll
      for (int r = 0; r < 4; ++r)
        Pw[(ns >> 1) * 512 + (quad * 4 + r) * 32 + (ns & 1) * 16 + c16] = f2bf(pv[ns][r]);
    asm volatile("s_waitcnt lgkmcnt(0)" ::: "memory");
    short8 pf[4];
#pragma unroll
    for (int c = 0; c < 4; ++c)
      pf[c] = *(const short8*)(Pw + c * 512 + c16 * 32 + quad * 8);

    // rescale O then accumulate P*V over 128 keys
#pragma unroll
    for (int nt = 0; nt < 8; ++nt)
#pragma unroll
      for (int r = 0; r < 4; ++r) o_acc[nt][r] *= alpha[r];
#pragma unroll
    for (int nt = 0; nt < 8; ++nt) {
      const int rr = nt * 16 + c16;
#pragma unroll
      for (int c = 0; c < 4; ++c) {
        short8 vf = *(const short8*)(Vlds + rr * 128 + (((c * 4 + quad) ^ c16) * 8));
        o_acc[nt] = __builtin_amdgcn_mfma_f32_16x16x32_bf16(pf[c], vf, o_acc[nt], 0, 0, 0);
      }
    }
  }

  // epilogue: O / l
#pragma unroll
  for (int r = 0; r < 4; ++r) {
    const float inv = 1.0f / fmaxf(l_run[r], 1e-20f);
    const int qrow = q0 + quad * 4 + r;
#pragma unroll
    for (int nt = 0; nt < 8; ++nt)
      O[(size_t)qrow * DM + head * DH + nt * 16 + c16] = f2bf(o_acc[nt][r] * inv);
  }
}

extern "C" void kernel_launch(void* const* d_in, const int* in_sizes, int n_in,
                              void* d_out, int out_size, void* d_ws, size_t ws_size,
                              hipStream_t stream) {
  const float* x    = (const float*)d_in[0];
  const float* cosb = (const float*)d_in[1];
  const float* sinb = (const float*)d_in[2];
  const int*   am   = (const int*)d_in[3];
  const float* lnw  = (const float*)d_in[4];
  const float* Wq   = (const float*)d_in[5];
  const float* Wk   = (const float*)d_in[6];
  const float* Wv   = (const float*)d_in[7];
  const float* Wo   = (const float*)d_in[8];
  float* out = (float*)d_out;

  u16t* h    = (u16t*)d_ws;                 // (T, D) bf16
  u16t* Q    = h + (size_t)TS * DM;         // (T, D)
  u16t* K    = Q + (size_t)TS * DM;         // (T, D)
  u16t* Vt   = K + (size_t)TS * DM;         // (D, T)  transposed V
  u16t* attn = Vt + (size_t)TS * DM;        // (T, D)
  u16t* Wb   = attn + (size_t)TS * DM;      // 4 x (D, D) bf16: q,k,v,o
  u16t* Wqb = Wb;
  u16t* Wkb = Wb + (size_t)DM * DM;
  u16t* Wvb = Wb + 2 * (size_t)DM * DM;
  u16t* Wob = Wb + 3 * (size_t)DM * DM;

  cast_weights<<<(4 * DM * DM / 4) / 256, 256, 0, stream>>>(Wq, Wk, Wv, Wo, Wb);
  rmsnorm_kernel<<<TS, 256, 0, stream>>>(x, lnw, h);
  gemm_bt<0><<<dim3(16, 16, 3), 256, 0, stream>>>(h, Wqb, Wkb, Wvb, Q, K, Vt, nullptr, nullptr);
  rope_kernel<<<(2 * TS * 1024) / 256, 256, 0, stream>>>(Q, K, cosb, sinb);
  attn_kernel<<<NH * (TS / 64), 256, 0, stream>>>(Q, K, Vt, am, attn);
  gemm_bt<1><<<dim3(16, 16, 1), 256, 0, stream>>>(attn, Wob, nullptr, nullptr, out, nullptr, nullptr, x, am);
}

// Round 8
// 331.972 us; speedup vs baseline: 1.2450x; 1.0021x over previous
//
#include <hip/hip_runtime.h>
#include <stdint.h>

#define TS 2048
#define DM 2048
#define NH 16
#define DH 128

typedef unsigned short u16t;
typedef __attribute__((ext_vector_type(8))) short short8;
typedef __attribute__((ext_vector_type(4))) float f32x4;
typedef __attribute__((ext_vector_type(4))) unsigned int u32x4;

__device__ __forceinline__ float bf2f(u16t b) {
  return __uint_as_float(((unsigned int)b) << 16);
}
__device__ __forceinline__ u16t f2bf(float f) {
  unsigned int u = __float_as_uint(f);
  u += 0x7FFFu + ((u >> 16) & 1u);   // round-to-nearest-even
  return (u16t)(u >> 16);
}

// async global->LDS, 16B per lane. LDS dest = wave-uniform base + lane*16.
__device__ __forceinline__ void async_copy16(const u16t* g, u16t* l) {
  __builtin_amdgcn_global_load_lds((const __attribute__((address_space(1))) void*)g,
                                   (__attribute__((address_space(3))) void*)l, 16, 0, 0);
}

// DPP row_ror within 16-lane rows: pure-VALU cross-lane (vs ds_bpermute for __shfl).
#define DPP_ROR_F(x, n) __uint_as_float(__builtin_amdgcn_update_dpp( \
    0, (int)__float_as_uint(x), 0x120 | (n), 0xF, 0xF, true))

__device__ __forceinline__ float row16_max(float x) {
  x = fmaxf(x, DPP_ROR_F(x, 8));
  x = fmaxf(x, DPP_ROR_F(x, 4));
  x = fmaxf(x, DPP_ROR_F(x, 2));
  x = fmaxf(x, DPP_ROR_F(x, 1));
  return x;
}
__device__ __forceinline__ float row16_sum(float x) {
  x += DPP_ROR_F(x, 8);
  x += DPP_ROR_F(x, 4);
  x += DPP_ROR_F(x, 2);
  x += DPP_ROR_F(x, 1);
  return x;
}

// ---------------- fp32 weights -> bf16 (4 matrices, ws) ----------------
__global__ __launch_bounds__(256) void cast_weights(const float* __restrict__ W0,
                                                    const float* __restrict__ W1,
                                                    const float* __restrict__ W2,
                                                    const float* __restrict__ W3,
                                                    u16t* __restrict__ out) {
  const int idx = blockIdx.x * 256 + threadIdx.x;   // 4M threads, 4 elems each
  const int mat = idx >> 20;
  const size_t off = (size_t)(idx & 0xFFFFF) * 4;
  const float* W = (mat == 0) ? W0 : (mat == 1) ? W1 : (mat == 2) ? W2 : W3;
  const f32x4 v = *(const f32x4*)(W + off);
  union { u16t s[4]; uint64_t u; } o;
#pragma unroll
  for (int i = 0; i < 4; ++i) o.s[i] = f2bf(v[i]);
  *(uint64_t*)(out + (size_t)mat * (DM * DM) + off) = o.u;
}

// ---------------- RMSNorm: h = bf16( ln_w * x * rsqrt(mean(x^2)+eps) ) ----------------
__global__ __launch_bounds__(256) void rmsnorm_kernel(const float* __restrict__ x,
                                                      const float* __restrict__ w,
                                                      u16t* __restrict__ h) {
  const int row = blockIdx.x;
  const int tid = threadIdx.x;
  const float* xr = x + (size_t)row * DM + tid * 8;
  f32x4 v0 = *(const f32x4*)(xr);
  f32x4 v1 = *(const f32x4*)(xr + 4);
  float f[8];
#pragma unroll
  for (int i = 0; i < 4; ++i) { f[i] = v0[i]; f[i + 4] = v1[i]; }
  float ss = 0.f;
#pragma unroll
  for (int i = 0; i < 8; ++i) ss += f[i] * f[i];
#pragma unroll
  for (int off = 1; off < 64; off <<= 1) ss += __shfl_xor(ss, off, 64);
  __shared__ float wsum[4];
  if ((tid & 63) == 0) wsum[tid >> 6] = ss;
  __syncthreads();
  float tot = wsum[0] + wsum[1] + wsum[2] + wsum[3];
  float rs = rsqrtf(tot * (1.0f / DM) + 1e-5f);
  f32x4 w0 = *(const f32x4*)(w + tid * 8);
  f32x4 w1 = *(const f32x4*)(w + tid * 8 + 4);
  u32x4 o;
#pragma unroll
  for (int i = 0; i < 4; ++i) {
    unsigned int lo = f2bf(f[2 * i]     * ((2 * i     < 4) ? w0[2 * i]     : w1[2 * i - 4]) * rs);
    unsigned int hi = f2bf(f[2 * i + 1] * ((2 * i + 1 < 4) ? w0[2 * i + 1] : w1[2 * i - 3]) * rs);
    o[i] = lo | (hi << 16);
  }
  *(u32x4*)(h + (size_t)row * DM + tid * 8) = o;
}

// ---------------- GEMM C = A * B^T (bf16 A,B row-major, K contiguous) ----------------
// Round-3 structure: 128x128 tile, BK=32, 4 waves each 64x64 (4x4 of 16x16x32 MFMA).
// 6.3M LDS bank conflicts measured harmless (r4); epilogue fusions measured harmful (r5).
// MODE 0: QKV fused via blockIdx.z (z==2 stores transposed for Vt); bf16 C.
// MODE 1: out-proj split-K=2 via blockIdx.z: plain fp32 partial store to C0/C1
//         (residual+mask applied by combine_kernel; no atomics — r5 lesson).
template <int MODE>
__global__ __launch_bounds__(256) void gemm_bt(
    const u16t* __restrict__ A,
    const u16t* __restrict__ B0, const u16t* __restrict__ B1, const u16t* __restrict__ B2,
    void* __restrict__ C0, void* __restrict__ C1, void* __restrict__ C2) {
  __shared__ u16t Alds[128 * 32];
  __shared__ u16t Blds[128 * 32];
  const int tid  = threadIdx.x;
  const int wave = tid >> 6;
  const int lane = tid & 63;
  const int m0 = blockIdx.y * 128;
  const int n0 = blockIdx.x * 128;
  const int z  = blockIdx.z;
  const u16t* B = (MODE == 0) ? (z == 0 ? B0 : (z == 1 ? B1 : B2)) : B0;
  const int kbeg = (MODE == 1) ? z * (DM / 2) : 0;
  const int kend = (MODE == 1) ? kbeg + (DM / 2) : DM;

  const f32x4 fzero = {0.f, 0.f, 0.f, 0.f};
  f32x4 acc[4][4];
#pragma unroll
  for (int i = 0; i < 4; ++i)
#pragma unroll
    for (int j = 0; j < 4; ++j) acc[i][j] = fzero;

  const int lr = lane >> 2;   // 0..15 row within 16-row chunk
  const int lc = lane & 3;    // 0..3  8-elem column chunk
  const int mw = (wave >> 1) * 64;
  const int nw = (wave & 1) * 64;
  const int quad = lane >> 4;
  const int c16  = lane & 15;

  for (int k0 = kbeg; k0 < kend; k0 += 32) {
    __syncthreads();
#pragma unroll
    for (int c = 0; c < 2; ++c) {
      const int ch = wave * 2 + c;        // 8 chunks of 1KB each per tile
      const int r  = ch * 16 + lr;
      async_copy16(A + (size_t)(m0 + r) * DM + k0 + lc * 8, Alds + ch * 512);
      async_copy16(B + (size_t)(n0 + r) * DM + k0 + lc * 8, Blds + ch * 512);
    }
    __syncthreads();
    short8 af[4], bfr[4];
#pragma unroll
    for (int mt = 0; mt < 4; ++mt)
      af[mt] = *(const short8*)(Alds + (mw + mt * 16 + c16) * 32 + quad * 8);
#pragma unroll
    for (int nt = 0; nt < 4; ++nt)
      bfr[nt] = *(const short8*)(Blds + (nw + nt * 16 + c16) * 32 + quad * 8);
#pragma unroll
    for (int mt = 0; mt < 4; ++mt)
#pragma unroll
      for (int nt = 0; nt < 4; ++nt)
        acc[mt][nt] = __builtin_amdgcn_mfma_f32_16x16x32_bf16(af[mt], bfr[nt], acc[mt][nt], 0, 0, 0);
  }

#pragma unroll
  for (int mt = 0; mt < 4; ++mt) {
#pragma unroll
    for (int r = 0; r < 4; ++r) {
      const int row = m0 + mw + mt * 16 + quad * 4 + r;
#pragma unroll
      for (int nt = 0; nt < 4; ++nt) {
        const int col = n0 + nw + nt * 16 + c16;
        float vv = acc[mt][nt][r];
        if (MODE == 1) {
          float* C = (float*)(z == 0 ? C0 : C1);
          C[(size_t)row * DM + col] = vv;
        } else {
          u16t* C = (u16t*)(z == 0 ? C0 : (z == 1 ? C1 : C2));
          if (z == 2) C[(size_t)col * TS + row] = f2bf(vv);   // Vt[d_global][t]
          else        C[(size_t)row * DM + col] = f2bf(vv);
        }
      }
    }
  }
}

// ---------------- combine: out = x + mask_row * (P0 + P1) ----------------
__global__ __launch_bounds__(256) void combine_kernel(const float* __restrict__ P0,
                                                      const float* __restrict__ P1,
                                                      const float* __restrict__ x,
                                                      const int* __restrict__ am,
                                                      float* __restrict__ out) {
  const size_t idx = ((size_t)blockIdx.x * 256 + threadIdx.x) * 4;
  const int row = (int)(idx >> 11);           // idx / DM
  const float mk = (am[row] != 0) ? 1.f : 0.f;
  const f32x4 a = *(const f32x4*)(P0 + idx);
  const f32x4 b = *(const f32x4*)(P1 + idx);
  const f32x4 xr = *(const f32x4*)(x + idx);
  f32x4 o;
#pragma unroll
  for (int i = 0; i < 4; ++i) o[i] = xr[i] + mk * (a[i] + b[i]);
  *(f32x4*)(out + idx) = o;
}

// ---------------- RoPE in-place on Q and K (bf16), fp32 cos/sin ----------------
__global__ __launch_bounds__(256) void rope_kernel(u16t* __restrict__ Q, u16t* __restrict__ K,
                                                   const float* __restrict__ cosb,
                                                   const float* __restrict__ sinb) {
  int idx = blockIdx.x * 256 + threadIdx.x;   // 2 * 2048 * 1024 threads
  int mat = idx >> 21;
  int rem = idx & ((1 << 21) - 1);
  int t = rem >> 10;
  int p = rem & 1023;
  int head = p >> 6, d = p & 63;
  u16t* M = mat ? K : Q;
  size_t base = (size_t)t * DM + head * DH + d;
  float c = cosb[t * DH + d];
  float s = sinb[t * DH + d];
  float x1 = bf2f(M[base]);
  float x2 = bf2f(M[base + 64]);
  M[base]      = f2bf(x1 * c - x2 * s);
  M[base + 64] = f2bf(x2 * c + x1 * s);
}

// ---------------- Flash attention (causal), LDS-staged K/V, 128-key tiles ----------------
// DPP rotate-reduce softmax (no ds_bpermute); single-buffered (dbuf neutral, r6).
__global__ __launch_bounds__(256) void attn_kernel(const u16t* __restrict__ Q,
                                                   const u16t* __restrict__ K,
                                                   const u16t* __restrict__ Vt,
                                                   const int* __restrict__ am,
                                                   u16t* __restrict__ O) {
  __shared__ u16t Klds[128 * 128];   // [key][d], swizzled granules, 32 KB
  __shared__ u16t Vlds[128 * 128];   // [d][key], swizzled granules, 32 KB
  __shared__ u16t Plds[4][2048];     // per-wave P: 4 chunks of 16x32, 16 KB
  const int wave = threadIdx.x >> 6;
  const int lane = threadIdx.x & 63;
  const int head = blockIdx.x & (NH - 1);
  const int qt   = (TS / 64 - 1) - (blockIdx.x >> 4);   // largest q-tiles first
  const int q0   = qt * 64 + wave * 16;
  const int quad = lane >> 4;
  const int c16  = lane & 15;
  const u16t* Qh  = Q + head * DH;
  const u16t* Kh  = K + head * DH;
  const u16t* Vth = Vt + (size_t)head * DH * TS;
  u16t* Pw = Plds[wave];

  // staging lane constants: chunk = 4 rows x 16 granules (16B each)
  const int row_s = (lane >> 4);    // 0..3 row within chunk
  const int g_s   = (lane & 15);    // granule slot

  short8 qf[4];
#pragma unroll
  for (int dc = 0; dc < 4; ++dc)
    qf[dc] = *(const short8*)(Qh + (size_t)(q0 + c16) * DM + dc * 32 + quad * 8);

  const f32x4 fzero = {0.f, 0.f, 0.f, 0.f};
  float m_run[4], l_run[4];
  f32x4 o_acc[8];
#pragma unroll
  for (int r = 0; r < 4; ++r) { m_run[r] = -1e30f; l_run[r] = 0.f; }
#pragma unroll
  for (int nt = 0; nt < 8; ++nt) o_acc[nt] = fzero;

  const float scale = 0.08838834764831845f;  // 1/sqrt(128)
  const int ntiles = (qt * 64 + 191) >> 7;   // 128-wide tiles covering keys 0..q0+63

  for (int kt = 0; kt < ntiles; ++kt) {
    const int k0 = kt * 128;
    __syncthreads();   // all waves done reading previous K/V tile
    // stage K (32 chunks of 1KB) + V (32 chunks): 8+8 per wave
#pragma unroll
    for (int c = 0; c < 8; ++c) {
      const int ch = wave * 8 + c;
      const int r  = 4 * ch + row_s;           // 0..127
      const int g  = g_s ^ (r & 15);
      async_copy16(Kh + (size_t)(k0 + r) * DM + g * 8, Klds + ch * 512);
      async_copy16(Vth + (size_t)r * TS + k0 + g * 8, Vlds + ch * 512);
    }
    __syncthreads();   // drains vmcnt -> LDS tiles ready

    // S = Q K^T over 128 keys (8 groups of 16)
    f32x4 s[8];
#pragma unroll
    for (int ns = 0; ns < 8; ++ns) {
      f32x4 sa = fzero;
      const int rr = ns * 16 + c16;
#pragma unroll
      for (int dc = 0; dc < 4; ++dc) {
        short8 kf = *(const short8*)(Klds + rr * 128 + (((dc * 4 + quad) ^ c16) * 8));
        sa = __builtin_amdgcn_mfma_f32_16x16x32_bf16(qf[dc], kf, sa, 0, 0, 0);
      }
      s[ns] = sa;
    }

    // mask + scale + online softmax (DPP rotate-reduce within each 16-lane row)
    float pv[8][4], tmax[4];
#pragma unroll
    for (int r = 0; r < 4; ++r) tmax[r] = -1e30f;
#pragma unroll
    for (int ns = 0; ns < 8; ++ns) {
      const int key = k0 + ns * 16 + c16;
      const bool kok = (am[key] != 0);
#pragma unroll
      for (int r = 0; r < 4; ++r) {
        const int qrow = q0 + quad * 4 + r;
        float v = s[ns][r] * scale;
        if (key > qrow || !kok) v = -1e30f;
        pv[ns][r] = v;
        tmax[r] = fmaxf(tmax[r], v);
      }
    }
    float alpha[4], rsum[4];
#pragma unroll
    for (int r = 0; r < 4; ++r) {
      const float mn = fmaxf(m_run[r], row16_max(tmax[r]));
      alpha[r] = __expf(m_run[r] - mn);
      m_run[r] = mn;
      float rs = 0.f;
#pragma unroll
      for (int ns = 0; ns < 8; ++ns) {
        const float e = __expf(pv[ns][r] - mn);
        pv[ns][r] = e;
        rs += e;
      }
      rsum[r] = row16_sum(rs);
      l_run[r] = l_run[r] * alpha[r] + rsum[r];
    }

    // P: C-layout -> LDS (four 16x32 chunks) -> A-layout
#pragma unroll
    for (int ns = 0; ns < 8; ++ns)
#pragma unroll
      for (int r = 0; r < 4; ++r)
        Pw[(ns >> 1) * 512 + (quad * 4 + r) * 32 + (ns & 1) * 16 + c16] = f2bf(pv[ns][r]);
    asm volatile("s_waitcnt lgkmcnt(0)" ::: "memory");
    short8 pf[4];
#pragma unroll
    for (int c = 0; c < 4; ++c)
      pf[c] = *(const short8*)(Pw + c * 512 + c16 * 32 + quad * 8);

    // rescale O then accumulate P*V over 128 keys
#pragma unroll
    for (int nt = 0; nt < 8; ++nt)
#pragma unroll
      for (int r = 0; r < 4; ++r) o_acc[nt][r] *= alpha[r];
#pragma unroll
    for (int nt = 0; nt < 8; ++nt) {
      const int rr = nt * 16 + c16;
#pragma unroll
      for (int c = 0; c < 4; ++c) {
        short8 vf = *(const short8*)(Vlds + rr * 128 + (((c * 4 + quad) ^ c16) * 8));
        o_acc[nt] = __builtin_amdgcn_mfma_f32_16x16x32_bf16(pf[c], vf, o_acc[nt], 0, 0, 0);
      }
    }
  }

  // epilogue: O / l
#pragma unroll
  for (int r = 0; r < 4; ++r) {
    const float inv = 1.0f / fmaxf(l_run[r], 1e-20f);
    const int qrow = q0 + quad * 4 + r;
#pragma unroll
    for (int nt = 0; nt < 8; ++nt)
      O[(size_t)qrow * DM + head * DH + nt * 16 + c16] = f2bf(o_acc[nt][r] * inv);
  }
}

extern "C" void kernel_launch(void* const* d_in, const int* in_sizes, int n_in,
                              void* d_out, int out_size, void* d_ws, size_t ws_size,
                              hipStream_t stream) {
  const float* x    = (const float*)d_in[0];
  const float* cosb = (const float*)d_in[1];
  const float* sinb = (const float*)d_in[2];
  const int*   am   = (const int*)d_in[3];
  const float* lnw  = (const float*)d_in[4];
  const float* Wq   = (const float*)d_in[5];
  const float* Wk   = (const float*)d_in[6];
  const float* Wv   = (const float*)d_in[7];
  const float* Wo   = (const float*)d_in[8];
  float* out = (float*)d_out;

  u16t* h    = (u16t*)d_ws;                 // (T, D) bf16   [0, 8 MB)
  u16t* Q    = h + (size_t)TS * DM;         // (T, D)        [8, 16)
  u16t* K    = Q + (size_t)TS * DM;         // (T, D)        [16, 24)
  u16t* Vt   = K + (size_t)TS * DM;         // (D, T)        [24, 32)
  u16t* attn = Vt + (size_t)TS * DM;        // (T, D)        [32, 40)
  u16t* Wb   = attn + (size_t)TS * DM;      // 4 x (D, D)    [40, 72)
  u16t* Wqb = Wb;
  u16t* Wkb = Wb + (size_t)DM * DM;
  u16t* Wvb = Wb + 2 * (size_t)DM * DM;
  u16t* Wob = Wb + 3 * (size_t)DM * DM;
  // split-K partials alias h/Q (P0) and K/Vt (P1) — dead by out-proj time
  float* P0 = (float*)d_ws;                          // 16 MB fp32
  float* P1 = (float*)(((u16t*)d_ws) + 2 * (size_t)TS * DM);

  cast_weights<<<(4 * DM * DM / 4) / 256, 256, 0, stream>>>(Wq, Wk, Wv, Wo, Wb);
  rmsnorm_kernel<<<TS, 256, 0, stream>>>(x, lnw, h);
  gemm_bt<0><<<dim3(16, 16, 3), 256, 0, stream>>>(h, Wqb, Wkb, Wvb, Q, K, Vt);
  rope_kernel<<<(2 * TS * 1024) / 256, 256, 0, stream>>>(Q, K, cosb, sinb);
  attn_kernel<<<NH * (TS / 64), 256, 0, stream>>>(Q, K, Vt, am, attn);
  gemm_bt<1><<<dim3(16, 16, 2), 256, 0, stream>>>(attn, Wob, nullptr, nullptr, P0, P1, nullptr);
  combine_kernel<<<(TS * DM / 4) / 256, 256, 0, stream>>>(P0, P1, x, am, out);
}